// Round 9
// baseline (277.642 us; speedup 1.0000x reference)
//
#include <hip/hip_runtime.h>
#include <hip/hip_bf16.h>
#include <hip/hip_fp16.h>

typedef int   i32x4 __attribute__((ext_vector_type(4)));
typedef float f32x4 __attribute__((ext_vector_type(4)));

// global -> LDS direct DMA, 16B per lane, linear LDS dest (base + lane*16)
#define GLD16(gp, lp)                                                   \
  __builtin_amdgcn_global_load_lds(                                     \
      (const __attribute__((address_space(1))) unsigned int*)(gp),      \
      (__attribute__((address_space(3))) unsigned int*)(lp), 16, 0, 0)

// ---------- helpers ----------

__device__ inline float blk_absmax(float v, float* red) {
#pragma unroll
  for (int off = 32; off; off >>= 1) v = fmaxf(v, __shfl_xor(v, off));
  __syncthreads();                       // protect red[] reuse across calls
  if ((threadIdx.x & 63) == 0) red[threadIdx.x >> 6] = v;
  __syncthreads();
  return fmaxf(fmaxf(red[0], red[1]), fmaxf(red[2], red[3]));
}

__device__ inline float f16round(float s) {   // s.astype(f16).astype(f32)
  return __half2float(__float2half(s));
}

__device__ inline float qclip(float x, float s, float qmax) {
  return fminf(fmaxf(rintf(x / s), -qmax), qmax);   // rintf = round-half-even (matches jnp.round)
}

// ---------- fused input quant: one launch, three block ranges ----------
// blocks [0, M):                x-row quant  (qmax 127, fp32 scale, also zero s2b)
// blocks [M, M+rank):           v-row quant  (gathered; high 127 / low 7; f16 scale out)
// blocks [M+rank, M+rank+out_f): u-row gather quant (two reductions)
// All three are independent -> co-scheduled in one launch instead of serial.

__global__ __launch_bounds__(256) void quant_all_kernel(
    const float* __restrict__ x, const float* __restrict__ vw,
    const float* __restrict__ uw,
    const int* __restrict__ hi, const int* __restrict__ lo,
    int M, int r_high, int rank, int C,
    char* __restrict__ xq, float* __restrict__ xs,
    char* __restrict__ vq, float* __restrict__ vs,
    char* __restrict__ uq, float* __restrict__ ush, float* __restrict__ usl,
    unsigned* __restrict__ s2b) {
  __shared__ float red[4];
  int t = threadIdx.x;
  int b = blockIdx.x;
  if (b < M) {
    int row = b;
    int z = row * 256 + t;
    if (z < 2 * M) s2b[z] = 0u;          // zero per launch (graph replays)
    const float4* src = (const float4*)(x + (size_t)row * C);
    float4 v[4];
    float m = 0.f;
#pragma unroll
    for (int i = 0; i < 4; ++i) {
      v[i] = src[t + i * 256];
      m = fmaxf(m, fmaxf(fmaxf(fabsf(v[i].x), fabsf(v[i].y)),
                         fmaxf(fabsf(v[i].z), fabsf(v[i].w))));
    }
    m = blk_absmax(m, red);
    float s = fmaxf(m, 1e-8f) / 127.0f;   // x_scale stays fp32 (no f16 round)
    if (t == 0) xs[row] = s;
    char4* dst = (char4*)(xq + (size_t)row * C);
#pragma unroll
    for (int i = 0; i < 4; ++i) {
      char4 o;
      o.x = (char)qclip(v[i].x, s, 127.f);
      o.y = (char)qclip(v[i].y, s, 127.f);
      o.z = (char)qclip(v[i].z, s, 127.f);
      o.w = (char)qclip(v[i].w, s, 127.f);
      dst[t + i * 256] = o;
    }
  } else if (b < M + rank) {
    int vb = b - M;
    int srow; float qmax;
    if (vb < r_high) { srow = hi[vb]; qmax = 127.f; }
    else             { srow = lo[vb - r_high]; qmax = 7.f; }
    const float4* src = (const float4*)(vw + (size_t)srow * C);
    float4 v[4];
    float m = 0.f;
#pragma unroll
    for (int i = 0; i < 4; ++i) {
      v[i] = src[t + i * 256];
      m = fmaxf(m, fmaxf(fmaxf(fabsf(v[i].x), fabsf(v[i].y)),
                         fmaxf(fabsf(v[i].z), fabsf(v[i].w))));
    }
    m = blk_absmax(m, red);
    float s = fmaxf(m, 1e-8f) / qmax;     // quantize with fp32 scale
    if (t == 0) vs[vb] = f16round(s);     // output-scale goes through f16
    char4* dst = (char4*)(vq + (size_t)vb * C);
#pragma unroll
    for (int i = 0; i < 4; ++i) {
      char4 o;
      o.x = (char)qclip(v[i].x, s, qmax);
      o.y = (char)qclip(v[i].y, s, qmax);
      o.z = (char)qclip(v[i].z, s, qmax);
      o.w = (char)qclip(v[i].w, s, qmax);
      dst[t + i * 256] = o;
    }
  } else {
    int i = b - M - rank;
    const float* urow = uw + (size_t)i * rank;
    // high path (r_high == 256 == blockDim)
    float hv = urow[hi[t]];
    float mh = blk_absmax(fabsf(hv), red);
    float sh = fmaxf(mh, 1e-8f) / 127.f;
    uq[(size_t)i * rank + t] = (char)qclip(hv, sh, 127.f);
    if (t == 0) ush[i] = f16round(sh);
    // low path (768 = 3*256)
    float lv[3]; float ml = 0.f;
#pragma unroll
    for (int j = 0; j < 3; ++j) {
      lv[j] = urow[lo[t + j * 256]];
      ml = fmaxf(ml, fabsf(lv[j]));
    }
    ml = blk_absmax(ml, red);
    float sl = fmaxf(ml, 1e-8f) / 7.f;
#pragma unroll
    for (int j = 0; j < 3; ++j)
      uq[(size_t)i * rank + r_high + t + j * 256] = (char)qclip(lv[j], sl, 7.f);
    if (t == 0) usl[i] = f16round(sl);
  }
}

// ---------- re-quant of y1 (lean): scales precomputed by gemm1 atomics ----------
// s2b[row] = high-half absmax bits, s2b[M+row] = low-half absmax bits.

__global__ __launch_bounds__(256) void quant_y1_kernel(
    const float4* __restrict__ y1, char4* __restrict__ y1q,
    const unsigned* __restrict__ s2b, int M) {
  int total = M * 256;                    // rank/4 = 256 float4 per row
  for (int i = blockIdx.x * 256 + threadIdx.x; i < total;
       i += gridDim.x * 256) {
    int row = i >> 8, c4 = i & 255;
    float m = __uint_as_float(s2b[(c4 < 64 ? 0 : M) + row]);
    float s = fmaxf(m, 1e-8f) / 127.f;
    float4 v = y1[i];
    char4 o;
    o.x = (char)qclip(v.x, s, 127.f);
    o.y = (char)qclip(v.y, s, 127.f);
    o.z = (char)qclip(v.z, s, 127.f);
    o.w = (char)qclip(v.w, s, 127.f);
    y1q[i] = o;
  }
}

// ---------- GEMM geometry (round-4/8 best-known, int8) ----------
// Block tile 64(M) x 128(N), BK = 128 i8 elements (128 BYTES per LDS row).
// 256 threads = 4 waves in 2x2; wave tile 32x64 = 2x4 frags of
// mfma_i32_16x16x64_i8.  Single-buffer 2-barrier K-loop.  Staging:
// global_load_lds width=16, linear LDS dest; XOR swizzle g=(l&7)^(row&7)
// pre-applied to the GLOBAL source address (rule #21).
// *** DIAGNOSTIC THIS ROUND: gemm2 body repeats x2 (bit-identical output,
// idempotent) so its dispatch exceeds the harness fills (~76us) and lands
// in top-5 WITH counters.  To be reverted next round. ***

#define BM 64
#define BN 128
#define BKT 128   // i8 elements per K-tile = bytes per LDS row

__global__ __launch_bounds__(256, 4) void gemm1_kernel(
    const char* __restrict__ A,   // xq: M x K i8
    const char* __restrict__ B,   // vq: N x K i8
    const float* __restrict__ xs, const float* __restrict__ ws,
    float* __restrict__ Y, unsigned* __restrict__ s2b,
    int M, int N, int K, int r_high) {
  __shared__ char smA[BM * BKT];   // 8 KB
  __shared__ char smB[BN * BKT];   // 16 KB
  int m0 = blockIdx.y * BM, n0 = blockIdx.x * BN;
  int tid = threadIdx.x, l = tid & 63, w = tid >> 6;
  int wr = w >> 1, wc = w & 1;

  int rb = w * 8 + (l >> 3);                // 0..31
  int g  = (l & 7) ^ (rb & 7);              // pre-swizzled 16B group
  const char* pA = A + (size_t)(m0 + rb) * K + g * 16;
  const char* pB = B + (size_t)(n0 + rb) * K + g * 16;
  char* ldsA = smA + w * 1024;              // + l*16 linear per wave
  char* ldsB = smB + w * 1024;

  i32x4 acc[2][4] = {};
  for (int k0 = 0; k0 < K; k0 += BKT) {
    __syncthreads();
#pragma unroll
    for (int i = 0; i < 2; ++i)
      GLD16(pA + (size_t)i * 32 * K + k0, ldsA + i * 4096);
#pragma unroll
    for (int i = 0; i < 4; ++i)
      GLD16(pB + (size_t)i * 32 * K + k0, ldsB + i * 4096);
    __syncthreads();
#pragma unroll
    for (int kk = 0; kk < 2; ++kk) {
      i32x4 af[2], bb[4];
      int lk = kk * 4 + (l >> 4);
#pragma unroll
      for (int f = 0; f < 2; ++f) {
        int ar = wr * 32 + f * 16 + (l & 15);
        af[f] = *(const i32x4*)(smA + ar * 128 + ((lk ^ (ar & 7)) << 4));
      }
#pragma unroll
      for (int f = 0; f < 4; ++f) {
        int br = wc * 64 + f * 16 + (l & 15);
        bb[f] = *(const i32x4*)(smB + br * 128 + ((lk ^ (br & 7)) << 4));
      }
#pragma unroll
      for (int i2 = 0; i2 < 2; ++i2)
#pragma unroll
        for (int j2 = 0; j2 < 4; ++j2)
          acc[i2][j2] = __builtin_amdgcn_mfma_i32_16x16x64_i8(
              af[i2], bb[j2], acc[i2][j2], 0, 0, 0);
    }
  }
  // epilogue: store scaled y1 + per-row partial absmax -> atomicMax (bits).
  float pm[2][4] = {};
#pragma unroll
  for (int i2 = 0; i2 < 2; ++i2)
#pragma unroll
    for (int j2 = 0; j2 < 4; ++j2) {
      int col = n0 + wc * 64 + j2 * 16 + (l & 15);
      float cs = ws[col];
#pragma unroll
      for (int r = 0; r < 4; ++r) {
        int row = m0 + wr * 32 + i2 * 16 + (l >> 4) * 4 + r;
        float v = (float)acc[i2][j2][r] * xs[row] * cs;
        Y[(size_t)row * N + col] = v;
        pm[i2][r] = fmaxf(pm[i2][r], fabsf(v));
      }
    }
#pragma unroll
  for (int i2 = 0; i2 < 2; ++i2)
#pragma unroll
    for (int r = 0; r < 4; ++r) {
#pragma unroll
      for (int off = 1; off < 16; off <<= 1)
        pm[i2][r] = fmaxf(pm[i2][r], __shfl_xor(pm[i2][r], off));
    }
  if ((l & 15) == 0) {
    unsigned* dst = s2b + (n0 < r_high ? 0 : M);   // high cols -> [0,M)
#pragma unroll
    for (int i2 = 0; i2 < 2; ++i2)
#pragma unroll
      for (int r = 0; r < 4; ++r) {
        int row = m0 + wr * 32 + i2 * 16 + (l >> 4) * 4 + r;
        atomicMax(&dst[row], __float_as_uint(pm[i2][r]));
      }
  }
}

__global__ __launch_bounds__(256, 3) void gemm2_kernel(
    const char* __restrict__ A,   // y1q: M x K i8
    const char* __restrict__ B,   // uq:  N x K i8
    const unsigned* __restrict__ s2b,
    const float* __restrict__ ush, const float* __restrict__ usl,
    const float* __restrict__ bias,
    float* __restrict__ Out, int M, int N, int K, int r_high) {
  __shared__ char smA[BM * BKT];
  __shared__ char smB[BN * BKT];
  int m0 = blockIdx.y * BM, n0 = blockIdx.x * BN;
  int tid = threadIdx.x, l = tid & 63, w = tid >> 6;
  int wr = w >> 1, wc = w & 1;

  int rb = w * 8 + (l >> 3);
  int g  = (l & 7) ^ (rb & 7);
  const char* pA = A + (size_t)(m0 + rb) * K + g * 16;
  const char* pB = B + (size_t)(n0 + rb) * K + g * 16;
  char* ldsA = smA + w * 1024;
  char* ldsB = smB + w * 1024;

  for (int rep = 0; rep < 2; ++rep) {   // DIAGNOSTIC x2 (idempotent)
    i32x4 acch[2][4] = {};
    i32x4 accl[2][4] = {};

    auto ktile = [&](int k0, i32x4(&acc)[2][4]) {
      __syncthreads();
#pragma unroll
      for (int i = 0; i < 2; ++i)
        GLD16(pA + (size_t)i * 32 * K + k0, ldsA + i * 4096);
#pragma unroll
      for (int i = 0; i < 4; ++i)
        GLD16(pB + (size_t)i * 32 * K + k0, ldsB + i * 4096);
      __syncthreads();
#pragma unroll
      for (int kk = 0; kk < 2; ++kk) {
        i32x4 af[2], bb[4];
        int lk = kk * 4 + (l >> 4);
#pragma unroll
        for (int f = 0; f < 2; ++f) {
          int ar = wr * 32 + f * 16 + (l & 15);
          af[f] = *(const i32x4*)(smA + ar * 128 + ((lk ^ (ar & 7)) << 4));
        }
#pragma unroll
        for (int f = 0; f < 4; ++f) {
          int br = wc * 64 + f * 16 + (l & 15);
          bb[f] = *(const i32x4*)(smB + br * 128 + ((lk ^ (br & 7)) << 4));
        }
#pragma unroll
        for (int i2 = 0; i2 < 2; ++i2)
#pragma unroll
          for (int j2 = 0; j2 < 4; ++j2)
            acc[i2][j2] = __builtin_amdgcn_mfma_i32_16x16x64_i8(
                af[i2], bb[j2], acc[i2][j2], 0, 0, 0);
      }
    };

    for (int k0 = 0; k0 < r_high; k0 += BKT) ktile(k0, acch);   // high
    for (int k0 = r_high; k0 < K; k0 += BKT) ktile(k0, accl);   // low

    float sh_[2][4], sl_[2][4];
#pragma unroll
    for (int i2 = 0; i2 < 2; ++i2)
#pragma unroll
      for (int r = 0; r < 4; ++r) {
        int row = m0 + wr * 32 + i2 * 16 + (l >> 4) * 4 + r;
        sh_[i2][r] = fmaxf(__uint_as_float(s2b[row]), 1e-8f) / 127.f;
        sl_[i2][r] = fmaxf(__uint_as_float(s2b[M + row]), 1e-8f) / 127.f;
      }

#pragma unroll
    for (int i2 = 0; i2 < 2; ++i2)
#pragma unroll
      for (int j2 = 0; j2 < 4; ++j2) {
        int col = n0 + wc * 64 + j2 * 16 + (l & 15);
        float uh = ush[col], ul = usl[col];
        float bc = f16round(bias[col]);
#pragma unroll
        for (int r = 0; r < 4; ++r) {
          int row = m0 + wr * 32 + i2 * 16 + (l >> 4) * 4 + r;
          Out[(size_t)row * N + col] =
              (float)acch[i2][j2][r] * (sh_[i2][r] * uh) +
              (float)accl[i2][j2][r] * (sl_[i2][r] * ul) + bc;
        }
      }
  }
}

// ---------- launch ----------

extern "C" void kernel_launch(void* const* d_in, const int* in_sizes, int n_in,
                              void* d_out, int out_size, void* d_ws, size_t ws_size,
                              hipStream_t stream) {
  const float* x    = (const float*)d_in[0];
  const float* uw   = (const float*)d_in[1];
  const float* vw   = (const float*)d_in[2];
  const float* bias = (const float*)d_in[3];
  const int*   hi   = (const int*)d_in[4];
  const int*   lo   = (const int*)d_in[5];

  const int in_f = 4096, out_f = 4096;
  const int rank   = in_sizes[1] / out_f;     // 1024
  const int r_high = in_sizes[4];             // 256
  const int M      = in_sizes[0] / in_f;      // 8192

  char* p = (char*)d_ws;
  auto take = [&](size_t bytes) {
    char* r = p;
    p += (bytes + 255) & ~(size_t)255;
    return r;
  };
  char*     xq  = take((size_t)M * in_f);
  float*    xs  = (float*)take((size_t)M * 4);
  char*     vq  = take((size_t)rank * in_f);
  float*    vs  = (float*)take((size_t)rank * 4);
  char*     uq  = take((size_t)out_f * rank);
  float*    ush = (float*)take((size_t)out_f * 4);
  float*    usl = (float*)take((size_t)out_f * 4);
  float*    y1  = (float*)take((size_t)M * rank * 4);
  char*     y1q = take((size_t)M * rank);
  unsigned* s2b = (unsigned*)take((size_t)2 * M * 4);

  quant_all_kernel<<<M + rank + out_f, 256, 0, stream>>>(
      x, vw, uw, hi, lo, M, r_high, rank, in_f,
      xq, xs, vq, vs, uq, ush, usl, s2b);
  gemm1_kernel<<<dim3(rank / BN, M / BM), 256, 0, stream>>>(
      xq, vq, xs, vs, y1, s2b, M, rank, in_f, r_high);
  quant_y1_kernel<<<4096, 256, 0, stream>>>(
      (const float4*)y1, (char4*)y1q, s2b, M);
  gemm2_kernel<<<dim3(out_f / BN, M / BM), 256, 0, stream>>>(
      y1q, uq, s2b, ush, usl, bias, (float*)d_out, M, out_f, rank, r_high);
}

// Round 10
// 156.245 us; speedup vs baseline: 1.7770x; 1.7770x over previous
//
#include <hip/hip_runtime.h>
#include <hip/hip_bf16.h>
#include <hip/hip_fp16.h>

typedef int   i32x4 __attribute__((ext_vector_type(4)));
typedef float f32x4 __attribute__((ext_vector_type(4)));

// global -> LDS direct DMA, 16B per lane, linear LDS dest (base + lane*16)
#define GLD16(gp, lp)                                                   \
  __builtin_amdgcn_global_load_lds(                                     \
      (const __attribute__((address_space(1))) unsigned int*)(gp),      \
      (__attribute__((address_space(3))) unsigned int*)(lp), 16, 0, 0)

// ---------- helpers ----------

__device__ inline float blk_absmax(float v, float* red) {
#pragma unroll
  for (int off = 32; off; off >>= 1) v = fmaxf(v, __shfl_xor(v, off));
  __syncthreads();                       // protect red[] reuse across calls
  if ((threadIdx.x & 63) == 0) red[threadIdx.x >> 6] = v;
  __syncthreads();
  return fmaxf(fmaxf(red[0], red[1]), fmaxf(red[2], red[3]));
}

__device__ inline float f16round(float s) {   // s.astype(f16).astype(f32)
  return __half2float(__float2half(s));
}

__device__ inline float qclip(float x, float s, float qmax) {
  return fminf(fmaxf(rintf(x / s), -qmax), qmax);   // rintf = round-half-even (matches jnp.round)
}

// ---------- fused input quant: one launch, three block ranges ----------
// blocks [0, M):                x-row quant  (qmax 127, fp32 scale, also zero s2b)
// blocks [M, M+rank):           v-row quant  (gathered; high 127 / low 7; f16 scale out)
// blocks [M+rank, M+rank+out_f): u-row gather quant (two reductions)

__global__ __launch_bounds__(256) void quant_all_kernel(
    const float* __restrict__ x, const float* __restrict__ vw,
    const float* __restrict__ uw,
    const int* __restrict__ hi, const int* __restrict__ lo,
    int M, int r_high, int rank, int C,
    char* __restrict__ xq, float* __restrict__ xs,
    char* __restrict__ vq, float* __restrict__ vs,
    char* __restrict__ uq, float* __restrict__ ush, float* __restrict__ usl,
    unsigned* __restrict__ s2b) {
  __shared__ float red[4];
  int t = threadIdx.x;
  int b = blockIdx.x;
  if (b < M) {
    int row = b;
    int z = row * 256 + t;
    if (z < 2 * M) s2b[z] = 0u;          // zero per launch (graph replays)
    const float4* src = (const float4*)(x + (size_t)row * C);
    float4 v[4];
    float m = 0.f;
#pragma unroll
    for (int i = 0; i < 4; ++i) {
      v[i] = src[t + i * 256];
      m = fmaxf(m, fmaxf(fmaxf(fabsf(v[i].x), fabsf(v[i].y)),
                         fmaxf(fabsf(v[i].z), fabsf(v[i].w))));
    }
    m = blk_absmax(m, red);
    float s = fmaxf(m, 1e-8f) / 127.0f;   // x_scale stays fp32 (no f16 round)
    if (t == 0) xs[row] = s;
    char4* dst = (char4*)(xq + (size_t)row * C);
#pragma unroll
    for (int i = 0; i < 4; ++i) {
      char4 o;
      o.x = (char)qclip(v[i].x, s, 127.f);
      o.y = (char)qclip(v[i].y, s, 127.f);
      o.z = (char)qclip(v[i].z, s, 127.f);
      o.w = (char)qclip(v[i].w, s, 127.f);
      dst[t + i * 256] = o;
    }
  } else if (b < M + rank) {
    int vb = b - M;
    int srow; float qmax;
    if (vb < r_high) { srow = hi[vb]; qmax = 127.f; }
    else             { srow = lo[vb - r_high]; qmax = 7.f; }
    const float4* src = (const float4*)(vw + (size_t)srow * C);
    float4 v[4];
    float m = 0.f;
#pragma unroll
    for (int i = 0; i < 4; ++i) {
      v[i] = src[t + i * 256];
      m = fmaxf(m, fmaxf(fmaxf(fabsf(v[i].x), fabsf(v[i].y)),
                         fmaxf(fabsf(v[i].z), fabsf(v[i].w))));
    }
    m = blk_absmax(m, red);
    float s = fmaxf(m, 1e-8f) / qmax;     // quantize with fp32 scale
    if (t == 0) vs[vb] = f16round(s);     // output-scale goes through f16
    char4* dst = (char4*)(vq + (size_t)vb * C);
#pragma unroll
    for (int i = 0; i < 4; ++i) {
      char4 o;
      o.x = (char)qclip(v[i].x, s, qmax);
      o.y = (char)qclip(v[i].y, s, qmax);
      o.z = (char)qclip(v[i].z, s, qmax);
      o.w = (char)qclip(v[i].w, s, qmax);
      dst[t + i * 256] = o;
    }
  } else {
    int i = b - M - rank;
    const float* urow = uw + (size_t)i * rank;
    // high path (r_high == 256 == blockDim)
    float hv = urow[hi[t]];
    float mh = blk_absmax(fabsf(hv), red);
    float sh = fmaxf(mh, 1e-8f) / 127.f;
    uq[(size_t)i * rank + t] = (char)qclip(hv, sh, 127.f);
    if (t == 0) ush[i] = f16round(sh);
    // low path (768 = 3*256)
    float lv[3]; float ml = 0.f;
#pragma unroll
    for (int j = 0; j < 3; ++j) {
      lv[j] = urow[lo[t + j * 256]];
      ml = fmaxf(ml, fabsf(lv[j]));
    }
    ml = blk_absmax(ml, red);
    float sl = fmaxf(ml, 1e-8f) / 7.f;
#pragma unroll
    for (int j = 0; j < 3; ++j)
      uq[(size_t)i * rank + r_high + t + j * 256] = (char)qclip(lv[j], sl, 7.f);
    if (t == 0) usl[i] = f16round(sl);
  }
}

// ---------- re-quant of y1 (lean): scales precomputed by gemm1 atomics ----------

__global__ __launch_bounds__(256) void quant_y1_kernel(
    const float4* __restrict__ y1, char4* __restrict__ y1q,
    const unsigned* __restrict__ s2b, int M) {
  int total = M * 256;                    // rank/4 = 256 float4 per row
  for (int i = blockIdx.x * 256 + threadIdx.x; i < total;
       i += gridDim.x * 256) {
    int row = i >> 8, c4 = i & 255;
    float m = __uint_as_float(s2b[(c4 < 64 ? 0 : M) + row]);
    float s = fmaxf(m, 1e-8f) / 127.f;
    float4 v = y1[i];
    char4 o;
    o.x = (char)qclip(v.x, s, 127.f);
    o.y = (char)qclip(v.y, s, 127.f);
    o.z = (char)qclip(v.z, s, 127.f);
    o.w = (char)qclip(v.w, s, 127.f);
    y1q[i] = o;
  }
}

// ---------- GEMM geometry (int8, best-known structure) ----------
// Block tile 64(M) x 128(N), BK = 128 i8 elements (128 BYTES per LDS row).
// 256 threads = 4 waves in 2x2; wave tile 32x64 = 2x4 frags of
// mfma_i32_16x16x64_i8.  Single-buffer 2-barrier K-loop.  Staging:
// global_load_lds width=16, linear LDS dest; XOR swizzle g=(l&7)^(row&7)
// pre-applied to the GLOBAL source address (rule #21).
// Round-9 PMC: gemm2 FETCH 110MB/rep vs 12MB compulsory -> Out-store RFO;
// fix: NONTEMPORAL Out stores (never re-read).  Occupancy 30.7% -> bound 4.

#define BM 64
#define BN 128
#define BKT 128   // i8 elements per K-tile = bytes per LDS row

__global__ __launch_bounds__(256, 4) void gemm1_kernel(
    const char* __restrict__ A,   // xq: M x K i8
    const char* __restrict__ B,   // vq: N x K i8
    const float* __restrict__ xs, const float* __restrict__ ws,
    float* __restrict__ Y, unsigned* __restrict__ s2b,
    int M, int N, int K, int r_high) {
  __shared__ char smA[BM * BKT];   // 8 KB
  __shared__ char smB[BN * BKT];   // 16 KB
  int m0 = blockIdx.y * BM, n0 = blockIdx.x * BN;
  int tid = threadIdx.x, l = tid & 63, w = tid >> 6;
  int wr = w >> 1, wc = w & 1;

  int rb = w * 8 + (l >> 3);                // 0..31
  int g  = (l & 7) ^ (rb & 7);              // pre-swizzled 16B group
  const char* pA = A + (size_t)(m0 + rb) * K + g * 16;
  const char* pB = B + (size_t)(n0 + rb) * K + g * 16;
  char* ldsA = smA + w * 1024;              // + l*16 linear per wave
  char* ldsB = smB + w * 1024;

  i32x4 acc[2][4] = {};
  for (int k0 = 0; k0 < K; k0 += BKT) {
    __syncthreads();
#pragma unroll
    for (int i = 0; i < 2; ++i)
      GLD16(pA + (size_t)i * 32 * K + k0, ldsA + i * 4096);
#pragma unroll
    for (int i = 0; i < 4; ++i)
      GLD16(pB + (size_t)i * 32 * K + k0, ldsB + i * 4096);
    __syncthreads();
#pragma unroll
    for (int kk = 0; kk < 2; ++kk) {
      i32x4 af[2], bb[4];
      int lk = kk * 4 + (l >> 4);
#pragma unroll
      for (int f = 0; f < 2; ++f) {
        int ar = wr * 32 + f * 16 + (l & 15);
        af[f] = *(const i32x4*)(smA + ar * 128 + ((lk ^ (ar & 7)) << 4));
      }
#pragma unroll
      for (int f = 0; f < 4; ++f) {
        int br = wc * 64 + f * 16 + (l & 15);
        bb[f] = *(const i32x4*)(smB + br * 128 + ((lk ^ (br & 7)) << 4));
      }
#pragma unroll
      for (int i2 = 0; i2 < 2; ++i2)
#pragma unroll
        for (int j2 = 0; j2 < 4; ++j2)
          acc[i2][j2] = __builtin_amdgcn_mfma_i32_16x16x64_i8(
              af[i2], bb[j2], acc[i2][j2], 0, 0, 0);
    }
  }
  // epilogue: store scaled y1 + per-row partial absmax -> atomicMax (bits).
  float pm[2][4] = {};
#pragma unroll
  for (int i2 = 0; i2 < 2; ++i2)
#pragma unroll
    for (int j2 = 0; j2 < 4; ++j2) {
      int col = n0 + wc * 64 + j2 * 16 + (l & 15);
      float cs = ws[col];
#pragma unroll
      for (int r = 0; r < 4; ++r) {
        int row = m0 + wr * 32 + i2 * 16 + (l >> 4) * 4 + r;
        float v = (float)acc[i2][j2][r] * xs[row] * cs;
        Y[(size_t)row * N + col] = v;      // y1 is re-read -> keep cached
        pm[i2][r] = fmaxf(pm[i2][r], fabsf(v));
      }
    }
#pragma unroll
  for (int i2 = 0; i2 < 2; ++i2)
#pragma unroll
    for (int r = 0; r < 4; ++r) {
#pragma unroll
      for (int off = 1; off < 16; off <<= 1)
        pm[i2][r] = fmaxf(pm[i2][r], __shfl_xor(pm[i2][r], off));
    }
  if ((l & 15) == 0) {
    unsigned* dst = s2b + (n0 < r_high ? 0 : M);   // high cols -> [0,M)
#pragma unroll
    for (int i2 = 0; i2 < 2; ++i2)
#pragma unroll
      for (int r = 0; r < 4; ++r) {
        int row = m0 + wr * 32 + i2 * 16 + (l >> 4) * 4 + r;
        atomicMax(&dst[row], __float_as_uint(pm[i2][r]));
      }
  }
}

__global__ __launch_bounds__(256, 4) void gemm2_kernel(
    const char* __restrict__ A,   // y1q: M x K i8
    const char* __restrict__ B,   // uq:  N x K i8
    const unsigned* __restrict__ s2b,
    const float* __restrict__ ush, const float* __restrict__ usl,
    const float* __restrict__ bias,
    float* __restrict__ Out, int M, int N, int K, int r_high) {
  __shared__ char smA[BM * BKT];
  __shared__ char smB[BN * BKT];
  int m0 = blockIdx.y * BM, n0 = blockIdx.x * BN;
  int tid = threadIdx.x, l = tid & 63, w = tid >> 6;
  int wr = w >> 1, wc = w & 1;

  int rb = w * 8 + (l >> 3);
  int g  = (l & 7) ^ (rb & 7);
  const char* pA = A + (size_t)(m0 + rb) * K + g * 16;
  const char* pB = B + (size_t)(n0 + rb) * K + g * 16;
  char* ldsA = smA + w * 1024;
  char* ldsB = smB + w * 1024;

  i32x4 acch[2][4] = {};
  i32x4 accl[2][4] = {};

  auto ktile = [&](int k0, i32x4(&acc)[2][4]) {
    __syncthreads();
#pragma unroll
    for (int i = 0; i < 2; ++i)
      GLD16(pA + (size_t)i * 32 * K + k0, ldsA + i * 4096);
#pragma unroll
    for (int i = 0; i < 4; ++i)
      GLD16(pB + (size_t)i * 32 * K + k0, ldsB + i * 4096);
    __syncthreads();
#pragma unroll
    for (int kk = 0; kk < 2; ++kk) {
      i32x4 af[2], bb[4];
      int lk = kk * 4 + (l >> 4);
#pragma unroll
      for (int f = 0; f < 2; ++f) {
        int ar = wr * 32 + f * 16 + (l & 15);
        af[f] = *(const i32x4*)(smA + ar * 128 + ((lk ^ (ar & 7)) << 4));
      }
#pragma unroll
      for (int f = 0; f < 4; ++f) {
        int br = wc * 64 + f * 16 + (l & 15);
        bb[f] = *(const i32x4*)(smB + br * 128 + ((lk ^ (br & 7)) << 4));
      }
#pragma unroll
      for (int i2 = 0; i2 < 2; ++i2)
#pragma unroll
        for (int j2 = 0; j2 < 4; ++j2)
          acc[i2][j2] = __builtin_amdgcn_mfma_i32_16x16x64_i8(
              af[i2], bb[j2], acc[i2][j2], 0, 0, 0);
    }
  };

  for (int k0 = 0; k0 < r_high; k0 += BKT) ktile(k0, acch);   // high
  for (int k0 = r_high; k0 < K; k0 += BKT) ktile(k0, accl);   // low

  // per-thread row scales from the atomic absmax bits (8 distinct rows)
  float sh_[2][4], sl_[2][4];
#pragma unroll
  for (int i2 = 0; i2 < 2; ++i2)
#pragma unroll
    for (int r = 0; r < 4; ++r) {
      int row = m0 + wr * 32 + i2 * 16 + (l >> 4) * 4 + r;
      sh_[i2][r] = fmaxf(__uint_as_float(s2b[row]), 1e-8f) / 127.f;
      sl_[i2][r] = fmaxf(__uint_as_float(s2b[M + row]), 1e-8f) / 127.f;
    }

#pragma unroll
  for (int i2 = 0; i2 < 2; ++i2)
#pragma unroll
    for (int j2 = 0; j2 < 4; ++j2) {
      int col = n0 + wc * 64 + j2 * 16 + (l & 15);
      float uh = ush[col], ul = usl[col];
      float bc = f16round(bias[col]);
#pragma unroll
      for (int r = 0; r < 4; ++r) {
        int row = m0 + wr * 32 + i2 * 16 + (l >> 4) * 4 + r;
        float v = (float)acch[i2][j2][r] * (sh_[i2][r] * uh) +
                  (float)accl[i2][j2][r] * (sl_[i2][r] * ul) + bc;
        // Out is never re-read: nontemporal store avoids RFO fetch of the
        // destination lines (round-9 PMC: 110MB/rep FETCH ~= Out size).
        __builtin_nontemporal_store(v, &Out[(size_t)row * N + col]);
      }
    }
}

// ---------- launch ----------

extern "C" void kernel_launch(void* const* d_in, const int* in_sizes, int n_in,
                              void* d_out, int out_size, void* d_ws, size_t ws_size,
                              hipStream_t stream) {
  const float* x    = (const float*)d_in[0];
  const float* uw   = (const float*)d_in[1];
  const float* vw   = (const float*)d_in[2];
  const float* bias = (const float*)d_in[3];
  const int*   hi   = (const int*)d_in[4];
  const int*   lo   = (const int*)d_in[5];

  const int in_f = 4096, out_f = 4096;
  const int rank   = in_sizes[1] / out_f;     // 1024
  const int r_high = in_sizes[4];             // 256
  const int M      = in_sizes[0] / in_f;      // 8192

  char* p = (char*)d_ws;
  auto take = [&](size_t bytes) {
    char* r = p;
    p += (bytes + 255) & ~(size_t)255;
    return r;
  };
  char*     xq  = take((size_t)M * in_f);
  float*    xs  = (float*)take((size_t)M * 4);
  char*     vq  = take((size_t)rank * in_f);
  float*    vs  = (float*)take((size_t)rank * 4);
  char*     uq  = take((size_t)out_f * rank);
  float*    ush = (float*)take((size_t)out_f * 4);
  float*    usl = (float*)take((size_t)out_f * 4);
  float*    y1  = (float*)take((size_t)M * rank * 4);
  char*     y1q = take((size_t)M * rank);
  unsigned* s2b = (unsigned*)take((size_t)2 * M * 4);

  quant_all_kernel<<<M + rank + out_f, 256, 0, stream>>>(
      x, vw, uw, hi, lo, M, r_high, rank, in_f,
      xq, xs, vq, vs, uq, ush, usl, s2b);
  gemm1_kernel<<<dim3(rank / BN, M / BM), 256, 0, stream>>>(
      xq, vq, xs, vs, y1, s2b, M, rank, in_f, r_high);
  quant_y1_kernel<<<4096, 256, 0, stream>>>(
      (const float4*)y1, (char4*)y1q, s2b, M);
  gemm2_kernel<<<dim3(out_f / BN, M / BM), 256, 0, stream>>>(
      y1q, uq, s2b, ush, usl, bias, (float*)d_out, M, out_f, rank, r_high);
}